// Round 6
// baseline (113.732 us; speedup 1.0000x reference)
//
#include <hip/hip_runtime.h>
#include <stdint.h>

#define NQ 10
#define NL 4

typedef unsigned int u32;
typedef _Float16 f16x8 __attribute__((ext_vector_type(8)));
typedef float f32x16 __attribute__((ext_vector_type(16)));
typedef u32 u32x4 __attribute__((ext_vector_type(4)));

// ---------- CNOT-ring permutation F (XOR-linear), closed form ----------
// F(i) = g0(g1(...g9(i))): b9=a9^a0, b8=a8^a9^a0, b_k=a_k^a_{k+1} (k=0..7).
constexpr u32 FRc(u32 r) {  // F(r<<5), r = 5-bit row
    u32 r0 = r & 1, r1 = (r >> 1) & 1, r2 = (r >> 2) & 1, r3 = (r >> 3) & 1, r4 = (r >> 4) & 1;
    return (r4 << 9) | ((r3 ^ r4) << 8) | ((r2 ^ r3) << 7) | ((r1 ^ r2) << 6) |
           ((r0 ^ r1) << 5) | (r0 << 4);
}
constexpr u32 FCc(u32 c) {  // F(c), c = 5-bit col
    u32 c0 = c & 1, c1 = (c >> 1) & 1, c2 = (c >> 2) & 1, c3 = (c >> 3) & 1, c4 = (c >> 4) & 1;
    return (c0 << 9) | (c0 << 8) | (c4 << 4) | ((c3 ^ c4) << 3) | ((c2 ^ c3) << 2) |
           ((c1 ^ c2) << 1) | (c0 ^ c1);
}
// F^-1 row/col sign masks (epilogue): bit_{9-q}(F^-1(r,c)) = par(r&Mrow_q) ^ par(c&Mcol_q)
// Mrow: q0=0x0F q1=0x18 q2=0x1C q3=0x1E q>=4=0x1F
// Mcol: q0=0x1F q1..4=0 q5=0x10 q6=0x18 q7=0x1C q8=0x1E q9=0x1F

// ---------- helpers ----------
__device__ __forceinline__ f32x16 mfma16(f16x8 a, f16x8 b, f32x16 c) {
    return __builtin_amdgcn_mfma_f32_32x32x16_f16(a, b, c, 0, 0, 0);
}
__device__ __forceinline__ f32x16 zero16() {
    f32x16 z;
#pragma unroll
    for (int i = 0; i < 16; i++) z[i] = 0.f;
    return z;
}
__device__ __forceinline__ f16x8 negf(f16x8 v) {
    u32x4 u = __builtin_bit_cast(u32x4, v);
#pragma unroll
    for (int i = 0; i < 4; i++) u[i] ^= 0x80008000u;
    return __builtin_bit_cast(f16x8, u);
}
__device__ __forceinline__ u32 pk2(float a, float b) {
    auto h = __builtin_amdgcn_cvt_pkrtz(a, b);
    return __builtin_bit_cast(u32, h);
}
__device__ __forceinline__ u32 permlo(u32 a, u32 b) { return __builtin_amdgcn_perm(b, a, 0x05040100u); }
__device__ __forceinline__ u32 permhi(u32 a, u32 b) { return __builtin_amdgcn_perm(b, a, 0x07060302u); }
__device__ __forceinline__ f16x8 mk8(u32 a, u32 b, u32 c, u32 d) {
    u32x4 v; v[0] = a; v[1] = b; v[2] = c; v[3] = d;
    return __builtin_bit_cast(f16x8, v);
}
template <int MASK>
__device__ __forceinline__ float swz(float v) {
    return __int_as_float(__builtin_amdgcn_ds_swizzle(__float_as_int(v), (MASK << 10) | 0x1F));
}
__device__ __forceinline__ u32 bpermu(int addr, u32 v) {
    return (u32)__builtin_amdgcn_ds_bpermute(addr, (int)v);
}
__device__ __forceinline__ void cmulh(float ar, float ai, float br, float bi, float& cr, float& ci) {
    cr = ar * br - ai * bi;
    ci = ar * bi + ai * br;
}

// C-layout f32x16 -> A/B-frag pair (f16) via in-register half-exchange.
// Own pair words pw[p] cover global k-pairs {0,1,4,5,8,9,12,13}+2h; exchange 4
// words with the other half (lane^32) to assemble kh0/kh1 frag word quads.
__device__ __forceinline__ void c2a(const f32x16& V, bool hb, int addr32, u32 (&o)[8]) {
    u32 pw[8];
#pragma unroll
    for (int p = 0; p < 8; p++) pw[p] = pk2(V[2 * p], V[2 * p + 1]);
    u32 s0 = hb ? pw[0] : pw[2];
    u32 s1 = hb ? pw[1] : pw[3];
    u32 s2 = hb ? pw[4] : pw[6];
    u32 s3 = hb ? pw[5] : pw[7];
    u32 r0 = bpermu(addr32, s0), r1 = bpermu(addr32, s1);
    u32 r2 = bpermu(addr32, s2), r3 = bpermu(addr32, s3);
    o[0] = hb ? r0 : pw[0]; o[1] = hb ? r1 : pw[1];
    o[2] = hb ? pw[2] : r0; o[3] = hb ? pw[3] : r1;
    o[4] = hb ? r2 : pw[4]; o[5] = hb ? r3 : pw[5];
    o[6] = hb ? pw[6] : r2; o[7] = hb ? pw[7] : r3;
}

// ---------- fused single kernel ----------
// LDS pool (u32 words): [0,8704): 34 frags (32 gate frags + 2 Srow) as f16x8/lane
//                       [8704,12800): prep K4 (8 x 16x16 cplx f32) / main per-wave slabs
//                       [12800,13120): 40 fused gates (fp32 x8)
__global__ __launch_bounds__(256) void tq_all(
    const float* __restrict__ x, const float* __restrict__ encW,
    const float* __restrict__ encb, const float* __restrict__ theta,
    float* __restrict__ out, int batch) {
    __shared__ u32 pool[13120];
    const int tid = threadIdx.x;
    float* gp = (float*)(pool + 12800);
    float2* K4p = (float2*)(pool + 8704);

    // ---- phase G: 40 fused gates Rx*Ry*Rz (row-vector convention) ----
    if (tid < NL * NQ) {
        float hx = 0.5f * theta[tid * 3 + 0];
        float hy = 0.5f * theta[tid * 3 + 1];
        float hz = 0.5f * theta[tid * 3 + 2];
        float cx = cosf(hx), sx = sinf(hx);
        float cy = cosf(hy), sy = sinf(hy);
        float cz = cosf(hz), sz = sinf(hz);
        float m00r = cx * cy, m00i = -sx * sy;
        float m01r = -cx * sy, m01i = -sx * cy;
        float m10r = cx * sy, m10i = -sx * cy;
        float m11r = cx * cy, m11i = sx * sy;
        float g00r, g00i, g01r, g01i, g10r, g10i, g11r, g11i;
        cmulh(m00r, m00i, cz, -sz, g00r, g00i);
        cmulh(m10r, m10i, cz, -sz, g10r, g10i);
        cmulh(m01r, m01i, cz, sz, g01r, g01i);
        cmulh(m11r, m11i, cz, sz, g11r, g11i);
        float* o = gp + tid * 8;
        o[0] = g00r; o[1] = g00i; o[2] = g01r; o[3] = g01i;
        o[4] = g10r; o[5] = g10i; o[6] = g11r; o[7] = g11i;
    }
    // ---- Srow sign frags (f=32,33): A[q][k] = (-1)^par(k & Mrow(q)) ----
    if (tid < 128) {
        int lane = tid & 63, kh = tid >> 6;
        int q = lane & 31, hf = (lane >> 5) & 1;
        u32 M = (q == 0) ? 0xFu : (q == 1) ? 0x18u : (q == 2) ? 0x1Cu : (q == 3) ? 0x1Eu : 0x1Fu;
        u32 w[4];
#pragma unroll
        for (int p = 0; p < 4; p++) {
            int k0 = kh * 16 + hf * 8 + 2 * p, k1 = k0 + 1;
            float v0 = (__builtin_popcount((u32)k0 & M) & 1) ? -1.f : 1.f;
            float v1 = (__builtin_popcount((u32)k1 & M) & 1) ? -1.f : 1.f;
            w[p] = pk2(v0, v1);
        }
        u32x4 v4; v4[0] = w[0]; v4[1] = w[1]; v4[2] = w[2]; v4[3] = w[3];
        *(u32x4*)(pool + (32 + kh) * 256 + lane * 4) = v4;
    }
    __syncthreads();
    // ---- phase K4: G0⊗G1⊗G2⊗G3 (16x16 cplx) per (l,mat) ----
#pragma unroll 1
    for (int rr = 0; rr < 8; rr++) {
        int e = rr * 256 + tid;
        int lm = e >> 8, idx = e & 255, k = idx >> 4, m = idx & 15;
        int gb = (lm >> 1) * 10 + (lm & 1) * 5;
        float pr = 1.f, pi = 0.f;
#pragma unroll
        for (int u = 0; u < 4; u++) {
            const float* gg = gp + (gb + u) * 8;
            int bi = (k >> (3 - u)) & 1, bo = (m >> (3 - u)) & 1;
            float er = gg[(bi * 2 + bo) * 2 + 0], ei = gg[(bi * 2 + bo) * 2 + 1];
            float nr, ni;
            cmulh(pr, pi, er, ei, nr, ni);
            pr = nr; pi = ni;
        }
        K4p[lm * 256 + idx] = make_float2(pr, pi);
    }
    __syncthreads();
    // ---- phase K5: ⊗G4 -> 32x32 frags (f16, frag f = lm*4 + part*2 + kh) ----
#pragma unroll 1
    for (int rr = 0; rr < 4; rr++) {
        int t = rr * 256 + tid;
        int lane = t & 63, kh = (t >> 6) & 1, lm = t >> 7;
        int m = lane & 31, hf = (lane >> 5) & 1;
        int gb = (lm >> 1) * 10 + (lm & 1) * 5;
        const float* g4 = gp + (gb + 4) * 8;
        int mu = m & 1;
        float e0r = g4[mu * 2 + 0], e0i = g4[mu * 2 + 1];
        float e1r = g4[(2 + mu) * 2 + 0], e1i = g4[(2 + mu) * 2 + 1];
        float2 kv[4];
#pragma unroll
        for (int jj = 0; jj < 4; jj++)
            kv[jj] = K4p[lm * 256 + (kh * 8 + hf * 4 + jj) * 16 + (m >> 1)];
        float vr[8], vi[8];
#pragma unroll
        for (int j = 0; j < 8; j++) {
            float2 a = kv[j >> 1];
            float er = (j & 1) ? e1r : e0r, ei = (j & 1) ? e1i : e0i;
            cmulh(a.x, a.y, er, ei, vr[j], vi[j]);
        }
        u32x4 wre, wim;
#pragma unroll
        for (int p = 0; p < 4; p++) {
            wre[p] = pk2(vr[2 * p], vr[2 * p + 1]);
            wim[p] = pk2(vi[2 * p], vi[2 * p + 1]);
        }
        *(u32x4*)(pool + (lm * 4 + kh) * 256 + lane * 4) = wre;
        *(u32x4*)(pool + (lm * 4 + 2 + kh) * 256 + lane * 4) = wim;
    }
    __syncthreads();

    // ================= main: one wave per sample =================
    int wave = blockIdx.x * 4 + (tid >> 6);
    int lane = tid & 63;
    if (wave >= batch) return;
    u32* slab = pool + 8704 + (tid >> 6) * 1024;
    const int col = lane & 31;
    const int half_ = lane >> 5;
    const bool hb = half_ != 0;
    const int addr32 = (lane ^ 32) << 2;
    const u32 Fc5 = FCc((u32)col);

    // ---- encoding: RY(enc) product state, built directly as B/A-frag ----
    float x0 = x[wave * 3 + 0], x1 = x[wave * 3 + 1], x2 = x[wave * 3 + 2];
    float hc = 1.f, hs = 0.f;
    if (lane < NQ) {
        float tta = 3.14159265358979323846f *
                    tanhf(x0 * encW[lane * 3 + 0] + x1 * encW[lane * 3 + 1] +
                          x2 * encW[lane * 3 + 2] + encb[lane]);
        float h = 0.5f * tta;
        hc = cosf(h);
        hs = sinf(h);
    }
    float fcv[NQ], fsv[NQ];
#pragma unroll
    for (int q = 0; q < NQ; q++) {
        fcv[q] = __shfl(hc, q, 64);
        fsv[q] = __shfl(hs, q, 64);
    }
    float colf = 1.f;
    colf *= ((col >> 4) & 1) ? -fsv[5] : fcv[5];
    colf *= ((col >> 3) & 1) ? -fsv[6] : fcv[6];
    colf *= ((col >> 2) & 1) ? -fsv[7] : fcv[7];
    colf *= ((col >> 1) & 1) ? -fsv[8] : fcv[8];
    colf *= (col & 1) ? -fsv[9] : fcv[9];
    float f1h = half_ ? -fsv[1] : fcv[1];
    float gj[8];
#pragma unroll
    for (int j = 0; j < 8; j++) {
        gj[j] = ((j & 4) ? -fsv[2] : fcv[2]) * ((j & 2) ? -fsv[3] : fcv[3]) *
                ((j & 1) ? -fsv[4] : fcv[4]);
    }
    f16x8 Sr0, Sr1, Si0, Si1;
#pragma unroll
    for (int j = 0; j < 8; j++) {
        Sr0[j] = (_Float16)(fcv[0] * f1h * gj[j] * colf);
        Sr1[j] = (_Float16)(-fsv[0] * f1h * gj[j] * colf);
        Si0[j] = (_Float16)0.f;
        Si1[j] = (_Float16)0.f;
    }

    const f16x8* FR = (const f16x8*)pool;
    f32x16 Ur, Ui;
#pragma unroll
    for (int l = 0; l < NL; l++) {
        f16x8 Wr0 = FR[(8 * l + 0) * 64 + lane], Wr1 = FR[(8 * l + 1) * 64 + lane];
        f16x8 Wi0 = FR[(8 * l + 2) * 64 + lane], Wi1 = FR[(8 * l + 3) * 64 + lane];
        f16x8 Vr0 = FR[(8 * l + 4) * 64 + lane], Vr1 = FR[(8 * l + 5) * 64 + lane];
        f16x8 Vi0 = FR[(8 * l + 6) * 64 + lane], Vi1 = FR[(8 * l + 7) * 64 + lane];

        // GEMM1': T' = S^T * W^T = T^T (S-frag reused as A; W-frag read as B)
        f32x16 Tr = zero16(), Ti = zero16();
        Tr = mfma16(Sr0, Wr0, Tr);
        Tr = mfma16(Sr1, Wr1, Tr);
        Ti = mfma16(Sr0, Wi0, Ti);
        Ti = mfma16(Sr1, Wi1, Ti);
        if (l > 0) {
            f16x8 nSi0 = negf(Si0), nSi1 = negf(Si1);
            Tr = mfma16(nSi0, Wi0, Tr);
            Tr = mfma16(nSi1, Wi1, Tr);
            Ti = mfma16(Si0, Wr0, Ti);
            Ti = mfma16(Si1, Wr1, Ti);
        }

        // C(T') -> A-frag(T): register half-exchange, no LDS
        u32 oR[8], oI[8];
        c2a(Tr, hb, addr32, oR);
        c2a(Ti, hb, addr32, oI);
        f16x8 TAr0 = mk8(oR[0], oR[1], oR[2], oR[3]);
        f16x8 TAr1 = mk8(oR[4], oR[5], oR[6], oR[7]);
        f16x8 TAi0 = mk8(oI[0], oI[1], oI[2], oI[3]);
        f16x8 TAi1 = mk8(oI[4], oI[5], oI[6], oI[7]);

        // GEMM2: U = T * V
        Ur = zero16();
        Ui = zero16();
        Ur = mfma16(TAr0, Vr0, Ur);
        Ur = mfma16(TAr1, Vr1, Ur);
        {
            f16x8 nTAi0 = negf(TAi0), nTAi1 = negf(TAi1);
            Ur = mfma16(nTAi0, Vi0, Ur);
            Ur = mfma16(nTAi1, Vi1, Ur);
        }
        Ui = mfma16(TAr0, Vi0, Ui);
        Ui = mfma16(TAr1, Vi1, Ui);
        Ui = mfma16(TAi0, Vr0, Ui);
        Ui = mfma16(TAi1, Vr1, Ui);

        if (l < NL - 1) {
            // RT2: CNOT permutation F via LDS; emit next-layer S frags
            {
                u32* wb = slab + col + half_ * (4 * 32);
#pragma unroll
                for (int gi = 0; gi < 16; gi++) {
                    int rb = (gi & 3) + 8 * (gi >> 2);
                    wb[rb * 32] = pk2(Ur[gi], Ui[gi]);
                }
            }
            u32 sb[16];
            {
                u32 fh = Fc5 ^ (half_ ? FRc(8) : 0u);
#pragma unroll
                for (int kh = 0; kh < 2; kh++)
#pragma unroll
                    for (int j = 0; j < 8; j++)
                        sb[kh * 8 + j] = slab[FRc(kh * 16 + j) ^ fh];
            }
            Sr0 = mk8(permlo(sb[0], sb[1]), permlo(sb[2], sb[3]),
                      permlo(sb[4], sb[5]), permlo(sb[6], sb[7]));
            Sr1 = mk8(permlo(sb[8], sb[9]), permlo(sb[10], sb[11]),
                      permlo(sb[12], sb[13]), permlo(sb[14], sb[15]));
            Si0 = mk8(permhi(sb[0], sb[1]), permhi(sb[2], sb[3]),
                      permhi(sb[4], sb[5]), permhi(sb[6], sb[7]));
            Si1 = mk8(permhi(sb[8], sb[9]), permhi(sb[10], sb[11]),
                      permhi(sb[12], sb[13]), permhi(sb[14], sb[15]));
        }
    }

    // ---- epilogue: D = Srow * P (MFMA), then col-signs + half-local reduce ----
    f32x16 P;
#pragma unroll
    for (int gi = 0; gi < 16; gi++) P[gi] = Ur[gi] * Ur[gi] + Ui[gi] * Ui[gi];
    u32 po[8];
    c2a(P, hb, addr32, po);
    f16x8 PB0 = mk8(po[0], po[1], po[2], po[3]);
    f16x8 PB1 = mk8(po[4], po[5], po[6], po[7]);
    f16x8 Srw0 = FR[32 * 64 + lane], Srw1 = FR[33 * 64 + lane];
    f32x16 D = mfma16(Srw0, PB0, mfma16(Srw1, PB1, zero16()));

    u32 b4 = (col >> 4) & 1, b3 = (col >> 3) & 1, b2 = (col >> 2) & 1,
        b1 = (col >> 1) & 1, b0 = col & 1;
    u32 p4 = b4, p43 = p4 ^ b3, p432 = p43 ^ b2, p4321 = p432 ^ b1, pall = p4321 ^ b0;
    // slots 0..5: h=0 -> q {0,1,2,3,8,9}; h=1 -> q {4,5,6,7,-,-}
    u32 sg[6];
    sg[0] = hb ? 0u : pall;
    sg[1] = hb ? p4 : 0u;
    sg[2] = hb ? p43 : 0u;
    sg[3] = hb ? p432 : 0u;
    sg[4] = hb ? 0u : p4321;
    sg[5] = hb ? 0u : pall;
    float red[6];
#pragma unroll
    for (int s = 0; s < 6; s++) {
        float v = __uint_as_float(__float_as_uint(D[s]) ^ (sg[s] << 31));
        v += swz<1>(v);
        v += swz<2>(v);
        v += swz<4>(v);
        v += swz<8>(v);
        v += swz<16>(v);
        red[s] = v;
    }
    int cc = col - ((col >= 4) ? 4 : 0);
    float v = red[0];
    v = (cc == 1) ? red[1] : v;
    v = (cc == 2) ? red[2] : v;
    v = (cc == 3) ? red[3] : v;
    v = (cc == 4) ? red[4] : v;
    v = (cc == 5) ? red[5] : v;
    bool st = hb ? (col >= 4 && col < 8) : (col < 4 || col == 8 || col == 9);
    if (st) out[wave * NQ + col] = v;
}

extern "C" void kernel_launch(void* const* d_in, const int* in_sizes, int n_in,
                              void* d_out, int out_size, void* d_ws, size_t ws_size,
                              hipStream_t stream) {
    const float* x = (const float*)d_in[0];
    const float* encW = (const float*)d_in[1];
    const float* encb = (const float*)d_in[2];
    const float* th = (const float*)d_in[3];
    float* out = (float*)d_out;
    int batch = in_sizes[0] / 3;
    int blocks = (batch + 3) / 4;
    tq_all<<<blocks, 256, 0, stream>>>(x, encW, encb, th, out, batch);
}

// Round 9
// 102.595 us; speedup vs baseline: 1.1086x; 1.1086x over previous
//
#include <hip/hip_runtime.h>
#include <stdint.h>

#define NQ 10
#define NL 4

typedef unsigned int u32;
typedef _Float16 f16x8 __attribute__((ext_vector_type(8)));
typedef float f32x16 __attribute__((ext_vector_type(16)));
typedef u32 u32x4 __attribute__((ext_vector_type(4)));

// ---------- CNOT-ring permutation F (XOR-linear), closed form ----------
// F(i) = g0(g1(...g9(i))): b9=a9^a0, b8=a8^a9^a0, b_k=a_k^a_{k+1} (k=0..7).
constexpr u32 FRc(u32 r) {  // F(r<<5), r = 5-bit row
    u32 r0 = r & 1, r1 = (r >> 1) & 1, r2 = (r >> 2) & 1, r3 = (r >> 3) & 1, r4 = (r >> 4) & 1;
    return (r4 << 9) | ((r3 ^ r4) << 8) | ((r2 ^ r3) << 7) | ((r1 ^ r2) << 6) |
           ((r0 ^ r1) << 5) | (r0 << 4);
}
constexpr u32 FCc(u32 c) {  // F(c), c = 5-bit col
    u32 c0 = c & 1, c1 = (c >> 1) & 1, c2 = (c >> 2) & 1, c3 = (c >> 3) & 1, c4 = (c >> 4) & 1;
    return (c0 << 9) | (c0 << 8) | (c4 << 4) | ((c3 ^ c4) << 3) | ((c2 ^ c3) << 2) |
           ((c1 ^ c2) << 1) | (c0 ^ c1);
}
// F^-1 sign masks: bit_{9-q}(F^-1(r,c)) = par(r&Mrow_q) ^ par(c&Mcol_q)
// Mrow: q0=0x0F q1=0x18 q2=0x1C q3=0x1E q>=4=0x1F
// Mcol: q0=0x1F q1..4=0 q5=0x10 q6=0x18 q7=0x1C q8=0x1E q9=0x1F

// ---------- helpers ----------
__device__ __forceinline__ f32x16 mfma16(f16x8 a, f16x8 b, f32x16 c) {
    return __builtin_amdgcn_mfma_f32_32x32x16_f16(a, b, c, 0, 0, 0);
}
__device__ __forceinline__ f32x16 zero16() {
    f32x16 z;
#pragma unroll
    for (int i = 0; i < 16; i++) z[i] = 0.f;
    return z;
}
__device__ __forceinline__ f16x8 negf(f16x8 v) {
    u32x4 u = __builtin_bit_cast(u32x4, v);
#pragma unroll
    for (int i = 0; i < 4; i++) u[i] ^= 0x80008000u;
    return __builtin_bit_cast(f16x8, u);
}
__device__ __forceinline__ u32 pk2(float a, float b) {
    auto h = __builtin_amdgcn_cvt_pkrtz(a, b);
    return __builtin_bit_cast(u32, h);
}
__device__ __forceinline__ u32 permlo(u32 a, u32 b) { return __builtin_amdgcn_perm(b, a, 0x05040100u); }
__device__ __forceinline__ u32 permhi(u32 a, u32 b) { return __builtin_amdgcn_perm(b, a, 0x07060302u); }
__device__ __forceinline__ f16x8 mk8(u32 a, u32 b, u32 c, u32 d) {
    u32x4 v; v[0] = a; v[1] = b; v[2] = c; v[3] = d;
    return __builtin_bit_cast(f16x8, v);
}
template <int MASK>
__device__ __forceinline__ float swz(float v) {
    return __int_as_float(__builtin_amdgcn_ds_swizzle(__float_as_int(v), (MASK << 10) | 0x1F));
}
__device__ __forceinline__ u32 bpermu(int addr, u32 v) {
    return (u32)__builtin_amdgcn_ds_bpermute(addr, (int)v);
}
__device__ __forceinline__ void cmulh(float ar, float ai, float br, float bi, float& cr, float& ci) {
    cr = ar * br - ai * bi;
    ci = ar * bi + ai * br;
}

// C-layout f32x16 -> A/B-frag pair (f16) via in-register half-exchange (R6-validated).
__device__ __forceinline__ void c2a(const f32x16& V, bool hb, int addr32, u32 (&o)[8]) {
    u32 pw[8];
#pragma unroll
    for (int p = 0; p < 8; p++) pw[p] = pk2(V[2 * p], V[2 * p + 1]);
    u32 s0 = hb ? pw[0] : pw[2];
    u32 s1 = hb ? pw[1] : pw[3];
    u32 s2 = hb ? pw[4] : pw[6];
    u32 s3 = hb ? pw[5] : pw[7];
    u32 r0 = bpermu(addr32, s0), r1 = bpermu(addr32, s1);
    u32 r2 = bpermu(addr32, s2), r3 = bpermu(addr32, s3);
    o[0] = hb ? r0 : pw[0]; o[1] = hb ? r1 : pw[1];
    o[2] = hb ? pw[2] : r0; o[3] = hb ? pw[3] : r1;
    o[4] = hb ? r2 : pw[4]; o[5] = hb ? r3 : pw[5];
    o[6] = hb ? pw[6] : r2; o[7] = hb ? pw[7] : r3;
}

// ---------- prep: fused gates -> Kronecker factors W,V (+ Srow signs) in d_ws ----------
// frag f = l*8 + mat*4 + part*2 + kh; element frag[(f*64+lane)*8+j]; f=32,33: Srow signs.
// Index space 2048 threads -> launch <<<2,1024>>>.
__global__ void tq_prep(const float* __restrict__ theta, uint16_t* __restrict__ frag) {
    __shared__ float g[NL * NQ][8];
    int tt = threadIdx.x;
    if (tt < NL * NQ) {
        float hx = 0.5f * theta[tt * 3 + 0];
        float hy = 0.5f * theta[tt * 3 + 1];
        float hz = 0.5f * theta[tt * 3 + 2];
        float cx = cosf(hx), sx = sinf(hx);
        float cy = cosf(hy), sy = sinf(hy);
        float cz = cosf(hz), sz = sinf(hz);
        float m00r = cx * cy, m00i = -sx * sy;
        float m01r = -cx * sy, m01i = -sx * cy;
        float m10r = cx * sy, m10i = -sx * cy;
        float m11r = cx * cy, m11i = sx * sy;
        float g00r, g00i, g01r, g01i, g10r, g10i, g11r, g11i;
        cmulh(m00r, m00i, cz, -sz, g00r, g00i);
        cmulh(m10r, m10i, cz, -sz, g10r, g10i);
        cmulh(m01r, m01i, cz, sz, g01r, g01i);
        cmulh(m11r, m11i, cz, sz, g11r, g11i);
        g[tt][0] = g00r; g[tt][1] = g00i; g[tt][2] = g01r; g[tt][3] = g01i;
        g[tt][4] = g10r; g[tt][5] = g10i; g[tt][6] = g11r; g[tt][7] = g11i;
    }
    __syncthreads();
    int t = blockIdx.x * blockDim.x + tt;  // 0..2047
    int lane = t & 63, kh = (t >> 6) & 1, part = (t >> 7) & 1, mat = (t >> 8) & 1, l = t >> 9;
    int mn = lane & 31, hf = (lane >> 5) & 1;
#pragma unroll
    for (int j = 0; j < 8; j++) {
        int k = kh * 16 + hf * 8 + j;
        float pr = 1.f, pi = 0.f;
#pragma unroll
        for (int u = 0; u < 5; u++) {
            int q = mat ? (5 + u) : u;
            int bi_ = (k >> (4 - u)) & 1;
            int bo_ = (mn >> (4 - u)) & 1;
            const float* gg = g[l * NQ + q];
            float er = gg[(bi_ * 2 + bo_) * 2 + 0];
            float ei = gg[(bi_ * 2 + bo_) * 2 + 1];
            float nr, ni;
            cmulh(pr, pi, er, ei, nr, ni);
            pr = nr;
            pi = ni;
        }
        float v = part ? pi : pr;
        _Float16 h = (_Float16)v;
        frag[t * 8 + j] = __builtin_bit_cast(unsigned short, h);
    }
    // Srow sign frags (f=32,33): A[m][k] = (-1)^par(k & Mrow(m)), m = lane&31
    if (blockIdx.x == 0 && tt < 128) {
        int ln = tt & 63, kh2 = tt >> 6;
        int q = ln & 31, hf2 = (ln >> 5) & 1;
        u32 M = (q == 0) ? 0xFu : (q == 1) ? 0x18u : (q == 2) ? 0x1Cu : (q == 3) ? 0x1Eu : 0x1Fu;
        uint16_t* o = frag + ((32 + kh2) * 64 + ln) * 8;
#pragma unroll
        for (int j = 0; j < 8; j++) {
            int k = kh2 * 16 + hf2 * 8 + j;
            float v = (__builtin_popcount((u32)k & M) & 1) ? -1.f : 1.f;
            _Float16 h = (_Float16)v;
            o[j] = __builtin_bit_cast(unsigned short, h);
        }
    }
}

// ---------- main: one wave per sample (256 threads = 4 waves; R5-proven packaging) ----------
__global__ __launch_bounds__(256) void tq_main(
    const float* __restrict__ x, const float* __restrict__ encW,
    const float* __restrict__ encb, const uint16_t* __restrict__ frag,
    float* __restrict__ out, int batch) {
    __shared__ u32 smem[4 * 1024];  // per-wave RT2 slabs only
    int tid = threadIdx.x;
    int wave = (blockIdx.x * blockDim.x + tid) >> 6;
    int lane = tid & 63;
    if (wave >= batch) return;
    u32* slab = smem + (tid >> 6) * 1024;
    const int col = lane & 31;
    const int half_ = lane >> 5;
    const bool hb = half_ != 0;
    const int addr32 = (lane ^ 32) << 2;
    const u32 Fc5 = FCc((u32)col);

    // ---- encoding: RY(enc) product state, built directly as B-frag ----
    float x0 = x[wave * 3 + 0], x1 = x[wave * 3 + 1], x2 = x[wave * 3 + 2];
    float hc = 1.f, hs = 0.f;
    if (lane < NQ) {
        float tta = 3.14159265358979323846f *
                    tanhf(x0 * encW[lane * 3 + 0] + x1 * encW[lane * 3 + 1] +
                          x2 * encW[lane * 3 + 2] + encb[lane]);
        float h = 0.5f * tta;
        hc = cosf(h);
        hs = sinf(h);
    }
    float fcv[NQ], fsv[NQ];
#pragma unroll
    for (int q = 0; q < NQ; q++) {
        fcv[q] = __shfl(hc, q, 64);
        fsv[q] = __shfl(hs, q, 64);
    }
    float colf = 1.f;
    colf *= ((col >> 4) & 1) ? -fsv[5] : fcv[5];
    colf *= ((col >> 3) & 1) ? -fsv[6] : fcv[6];
    colf *= ((col >> 2) & 1) ? -fsv[7] : fcv[7];
    colf *= ((col >> 1) & 1) ? -fsv[8] : fcv[8];
    colf *= (col & 1) ? -fsv[9] : fcv[9];
    float f1h = half_ ? -fsv[1] : fcv[1];
    float gj[8];
#pragma unroll
    for (int j = 0; j < 8; j++) {
        gj[j] = ((j & 4) ? -fsv[2] : fcv[2]) * ((j & 2) ? -fsv[3] : fcv[3]) *
                ((j & 1) ? -fsv[4] : fcv[4]);
    }
    f16x8 Sr0, Sr1, Si0, Si1;
#pragma unroll
    for (int j = 0; j < 8; j++) {
        Sr0[j] = (_Float16)(fcv[0] * f1h * gj[j] * colf);
        Sr1[j] = (_Float16)(-fsv[0] * f1h * gj[j] * colf);
        Si0[j] = (_Float16)0.f;
        Si1[j] = (_Float16)0.f;
    }

    const f16x8* fr = (const f16x8*)frag;
#define FRAG(f) fr[((f)*64) + lane]

    f32x16 Ur, Ui;
#pragma unroll
    for (int l = 0; l < NL; l++) {
        f16x8 Wr0 = FRAG(8 * l + 0), Wr1 = FRAG(8 * l + 1);
        f16x8 Wi0 = FRAG(8 * l + 2), Wi1 = FRAG(8 * l + 3);
        f16x8 Vr0 = FRAG(8 * l + 4), Vr1 = FRAG(8 * l + 5);
        f16x8 Vi0 = FRAG(8 * l + 6), Vi1 = FRAG(8 * l + 7);

        // GEMM1': T' = S^T * W^T = T^T (S-frag reused as A; W-frag read as B)
        f32x16 Tr = zero16(), Ti = zero16();
        Tr = mfma16(Sr0, Wr0, Tr);
        Tr = mfma16(Sr1, Wr1, Tr);
        Ti = mfma16(Sr0, Wi0, Ti);
        Ti = mfma16(Sr1, Wi1, Ti);
        if (l > 0) {
            f16x8 nSi0 = negf(Si0), nSi1 = negf(Si1);
            Tr = mfma16(nSi0, Wi0, Tr);
            Tr = mfma16(nSi1, Wi1, Tr);
            Ti = mfma16(Si0, Wr0, Ti);
            Ti = mfma16(Si1, Wr1, Ti);
        }

        // C(T') -> A-frag(T): register half-exchange, no LDS
        u32 oR[8], oI[8];
        c2a(Tr, hb, addr32, oR);
        c2a(Ti, hb, addr32, oI);
        f16x8 TAr0 = mk8(oR[0], oR[1], oR[2], oR[3]);
        f16x8 TAr1 = mk8(oR[4], oR[5], oR[6], oR[7]);
        f16x8 TAi0 = mk8(oI[0], oI[1], oI[2], oI[3]);
        f16x8 TAi1 = mk8(oI[4], oI[5], oI[6], oI[7]);

        // GEMM2: U = T * V
        Ur = zero16();
        Ui = zero16();
        Ur = mfma16(TAr0, Vr0, Ur);
        Ur = mfma16(TAr1, Vr1, Ur);
        {
            f16x8 nTAi0 = negf(TAi0), nTAi1 = negf(TAi1);
            Ur = mfma16(nTAi0, Vi0, Ur);
            Ur = mfma16(nTAi1, Vi1, Ur);
        }
        Ui = mfma16(TAr0, Vi0, Ui);
        Ui = mfma16(TAr1, Vi1, Ui);
        Ui = mfma16(TAi0, Vr0, Ui);
        Ui = mfma16(TAi1, Vr1, Ui);

        if (l < NL - 1) {
            // RT2: CNOT permutation F via per-wave LDS slab; emit next S frags
            {
                u32* wb = slab + col + half_ * (4 * 32);
#pragma unroll
                for (int gi = 0; gi < 16; gi++) {
                    int rb = (gi & 3) + 8 * (gi >> 2);
                    wb[rb * 32] = pk2(Ur[gi], Ui[gi]);
                }
            }
            u32 sb[16];
            {
                u32 fh = Fc5 ^ (half_ ? FRc(8) : 0u);
#pragma unroll
                for (int kh = 0; kh < 2; kh++)
#pragma unroll
                    for (int j = 0; j < 8; j++)
                        sb[kh * 8 + j] = slab[FRc(kh * 16 + j) ^ fh];
            }
            Sr0 = mk8(permlo(sb[0], sb[1]), permlo(sb[2], sb[3]),
                      permlo(sb[4], sb[5]), permlo(sb[6], sb[7]));
            Sr1 = mk8(permlo(sb[8], sb[9]), permlo(sb[10], sb[11]),
                      permlo(sb[12], sb[13]), permlo(sb[14], sb[15]));
            Si0 = mk8(permhi(sb[0], sb[1]), permhi(sb[2], sb[3]),
                      permhi(sb[4], sb[5]), permhi(sb[6], sb[7]));
            Si1 = mk8(permhi(sb[8], sb[9]), permhi(sb[10], sb[11]),
                      permhi(sb[12], sb[13]), permhi(sb[14], sb[15]));
        }
    }

    // ---- epilogue: D = Srow * P (MFMA), Srow frags from d_ws ----
    f32x16 P;
#pragma unroll
    for (int gi = 0; gi < 16; gi++) P[gi] = Ur[gi] * Ur[gi] + Ui[gi] * Ui[gi];
    u32 po[8];
    c2a(P, hb, addr32, po);
    f16x8 PB0 = mk8(po[0], po[1], po[2], po[3]);
    f16x8 PB1 = mk8(po[4], po[5], po[6], po[7]);
    f16x8 Srw0 = FRAG(32), Srw1 = FRAG(33);
    f32x16 D = mfma16(Srw0, PB0, mfma16(Srw1, PB1, zero16()));

    u32 b4 = (col >> 4) & 1, b3 = (col >> 3) & 1, b2 = (col >> 2) & 1,
        b1 = (col >> 1) & 1, b0 = col & 1;
    u32 p4 = b4, p43 = p4 ^ b3, p432 = p43 ^ b2, p4321 = p432 ^ b1, pall = p4321 ^ b0;
    // slots 0..5: h=0 -> q {0,1,2,3,8,9}; h=1 -> q {4,5,6,7,-,-}
    u32 sg[6];
    sg[0] = hb ? 0u : pall;
    sg[1] = hb ? p4 : 0u;
    sg[2] = hb ? p43 : 0u;
    sg[3] = hb ? p432 : 0u;
    sg[4] = hb ? 0u : p4321;
    sg[5] = hb ? 0u : pall;
    float red[6];
#pragma unroll
    for (int s = 0; s < 6; s++) {
        float v = __uint_as_float(__float_as_uint(D[s]) ^ (sg[s] << 31));
        v += swz<1>(v);
        v += swz<2>(v);
        v += swz<4>(v);
        v += swz<8>(v);
        v += swz<16>(v);
        red[s] = v;
    }
    int cc = col - ((col >= 4) ? 4 : 0);
    float v = red[0];
    v = (cc == 1) ? red[1] : v;
    v = (cc == 2) ? red[2] : v;
    v = (cc == 3) ? red[3] : v;
    v = (cc == 4) ? red[4] : v;
    v = (cc == 5) ? red[5] : v;
    bool st = hb ? (col >= 4 && col < 8) : (col < 4 || col == 8 || col == 9);
    if (st) out[wave * NQ + col] = v;
}

extern "C" void kernel_launch(void* const* d_in, const int* in_sizes, int n_in,
                              void* d_out, int out_size, void* d_ws, size_t ws_size,
                              hipStream_t stream) {
    const float* x = (const float*)d_in[0];
    const float* encW = (const float*)d_in[1];
    const float* encb = (const float*)d_in[2];
    const float* th = (const float*)d_in[3];
    float* out = (float*)d_out;
    uint16_t* frag = (uint16_t*)d_ws;  // 34 frags * 64 lanes * 8 f16 = 17408 f16 (~35 KB)
    int batch = in_sizes[0] / 3;

    tq_prep<<<2, 1024, 0, stream>>>(th, frag);
    int total_threads = batch * 64;
    tq_main<<<(total_threads + 255) / 256, 256, 0, stream>>>(x, encW, encb, frag, out, batch);
}